// Round 1
// baseline (1022.391 us; speedup 1.0000x reference)
//
#include <hip/hip_runtime.h>
#include <cmath>

typedef float f4_t __attribute__((ext_vector_type(4)));
typedef float f2_t __attribute__((ext_vector_type(2)));
typedef long  l2_t __attribute__((ext_vector_type(2)));

#define B_TOTAL   65536
#define FTW_SCALE 1024.0f
#define INV_SCALE (1.0f/1024.0f)
#define L1WT_OFF  (768 * 1024)

__device__ __forceinline__ int pk8(float a, float b, float c, float d) {
    int v = __builtin_amdgcn_cvt_pk_fp8_f32(a, b, 0, false);
    return  __builtin_amdgcn_cvt_pk_fp8_f32(c, d, v, true);
}
__device__ __forceinline__ float clip01(float x) { return fminf(fmaxf(x, 0.f), 1.f); }

// ---------------------------------------------------------------------------
// Pack ft_w [1024][768] fp32 -> fp8(e4m3, x1024) in frag-pair order:
//   ws[(kk*32 + ncp)*1024 + lane*16]  holds cols ncp*32+[0,32) for k-chunk kk
//   bytes 0-7 = cols +[0,16) frag, bytes 8-15 = cols +[16,32) frag.
// ---------------------------------------------------------------------------
__global__ void pack_ftw_kernel(const float* __restrict__ ftw, char* __restrict__ ws)
{
    int t    = blockIdx.x * 256 + threadIdx.x;   // 0..49151
    int lane = t & 63;
    int ncp  = (t >> 6) & 31;
    int kk   = t >> 11;                          // 0..23
    int nl = lane & 15, q = (lane >> 4) & 3;
    int k0 = kk * 32 + q * 8;
    const float* p0 = ftw + (size_t)(ncp * 32 + nl) * 768 + k0;
    const float* p1 = p0 + 16 * 768;
    float4 x0 = *(const float4*)p0;
    float4 x1 = *(const float4*)(p0 + 4);
    float4 y0 = *(const float4*)p1;
    float4 y1 = *(const float4*)(p1 + 4);
    int4 o;
    o.x = pk8(x0.x*FTW_SCALE, x0.y*FTW_SCALE, x0.z*FTW_SCALE, x0.w*FTW_SCALE);
    o.y = pk8(x1.x*FTW_SCALE, x1.y*FTW_SCALE, x1.z*FTW_SCALE, x1.w*FTW_SCALE);
    o.z = pk8(y0.x*FTW_SCALE, y0.y*FTW_SCALE, y0.z*FTW_SCALE, y0.w*FTW_SCALE);
    o.w = pk8(y1.x*FTW_SCALE, y1.y*FTW_SCALE, y1.z*FTW_SCALE, y1.w*FTW_SCALE);
    *(int4*)(ws + (size_t)t * 16) = o;
}

// ---------------------------------------------------------------------------
// Transpose l1_w [8][2048] -> l1wT [2048][8] so the fused epilogue loads one
// column's 8 output-weights as two contiguous dwordx2 pairs instead of 16
// stride-8KB scalar loads.
// ---------------------------------------------------------------------------
__global__ void pack_l1w_kernel(const float* __restrict__ l1w, float* __restrict__ l1wT)
{
    int t = blockIdx.x * 256 + threadIdx.x;   // 0..16383
    int c = t >> 3, o = t & 7;
    l1wT[t] = l1w[o * 2048 + c];
}

// one half-kg worth of MFMAs: 4 m-tiles x 2 n-frags against one B reg pair
#define HALF_STEP(AW, AB, BV)                                                                  \
    acc[0][0] = __builtin_amdgcn_mfma_f32_16x16x32_fp8_fp8((AW).x, (BV).x, acc[0][0], 0,0,0);  \
    acc[1][0] = __builtin_amdgcn_mfma_f32_16x16x32_fp8_fp8((AW).y, (BV).x, acc[1][0], 0,0,0);  \
    acc[2][0] = __builtin_amdgcn_mfma_f32_16x16x32_fp8_fp8((AB).x, (BV).x, acc[2][0], 0,0,0);  \
    acc[3][0] = __builtin_amdgcn_mfma_f32_16x16x32_fp8_fp8((AB).y, (BV).x, acc[3][0], 0,0,0);  \
    acc[0][1] = __builtin_amdgcn_mfma_f32_16x16x32_fp8_fp8((AW).x, (BV).y, acc[0][1], 0,0,0);  \
    acc[1][1] = __builtin_amdgcn_mfma_f32_16x16x32_fp8_fp8((AW).y, (BV).y, acc[1][1], 0,0,0);  \
    acc[2][1] = __builtin_amdgcn_mfma_f32_16x16x32_fp8_fp8((AB).x, (BV).y, acc[2][1], 0,0,0);  \
    acc[3][1] = __builtin_amdgcn_mfma_f32_16x16x32_fp8_fp8((AB).y, (BV).y, acc[3][1], 0,0,0);

#define KG_STEP(KG)                                                         \
    {                                                                       \
        l2_t aw  = *(const l2_t*)(ap + (2*(KG)) * 2048);                    \
        l2_t ab  = *(const l2_t*)(ap + (2*(KG)) * 2048 + 1024);             \
        HALF_STEP(aw, ab, bA0)                                              \
        l2_t aw2 = *(const l2_t*)(ap + (2*(KG)+1) * 2048);                  \
        l2_t ab2 = *(const l2_t*)(ap + (2*(KG)+1) * 2048 + 1024);           \
        HALF_STEP(aw2, ab2, bA1)                                            \
    }

// ---------------------------------------------------------------------------
// Fused kernel. 1 block = 32 samples; A (w+b, fp8) in LDS fragment order.
// This round: depth-3 B register pipeline (6 loads in flight, issue-to-use
// ~300cy >= L2 latency), cross-ng seed-prefetch hidden under the epilogue,
// and vectorized (transposed) l1w epilogue loads hoisted 3 kg-iters early.
// ---------------------------------------------------------------------------
__global__ __launch_bounds__(256, 3) void nnue_fused_kernel(
    const float* __restrict__ wf,  const float* __restrict__ bfeat,
    const float* __restrict__ stm, const char*  __restrict__ ftw8,
    const float* __restrict__ ftb, const float* __restrict__ l1wT,
    const float* __restrict__ l1b, const float* __restrict__ l2w,
    const float* __restrict__ l2b, const float* __restrict__ l3w,
    const float* __restrict__ l3b, float* __restrict__ out)
{
    __shared__ char  Ald[24 * 2048];      // 48 KB: [(kk*2+p)*1024 + lane*16]
    __shared__ float l1part[4][32][8];    // 4 KB

    const int t    = threadIdx.x;
    const int lane = t & 63;
    const int wave = t >> 6;
    const int nl   = lane & 15;
    const int q    = (lane >> 4) & 3;
    const int s0   = blockIdx.x * 32;

    // ---- stage A: fp32 -> fp8 directly into fragment-pair layout ----
    {
        const int kpar = t >> 7;
        const int tt   = t & 127;
        const int p    = tt >> 6;         // 0 = white, 1 = black
        const int sl   = tt & 63;
        const int snl  = sl & 15, sq = (sl >> 4) & 3;
        const float* base = p ? bfeat : wf;
        const float* r0 = base + (size_t)(s0 + snl) * 768;
        const float* r1 = r0 + 16 * 768;
        char* dst = &Ald[p * 1024 + sl * 16];
        #pragma unroll 4
        for (int pass = 0; pass < 12; ++pass) {
            int kk = pass * 2 + kpar;
            int k0 = kk * 32 + sq * 8;
            float4 x0 = *(const float4*)(r0 + k0);
            float4 x1 = *(const float4*)(r0 + k0 + 4);
            float4 y0 = *(const float4*)(r1 + k0);
            float4 y1 = *(const float4*)(r1 + k0 + 4);
            int4 o;
            o.x = pk8(x0.x, x0.y, x0.z, x0.w);   // rows 0-15
            o.y = pk8(x1.x, x1.y, x1.z, x1.w);
            o.z = pk8(y0.x, y0.y, y0.z, y0.w);   // rows 16-31
            o.w = pk8(y1.x, y1.y, y1.z, y1.w);
            *(int4*)(dst + kk * 2048) = o;
        }
    }

    float s_lo[4], s_hi[4];
    #pragma unroll
    for (int r = 0; r < 4; ++r) {
        s_lo[r] = stm[s0 + q * 4 + r];
        s_hi[r] = stm[s0 + 16 + q * 4 + r];
    }

    __syncthreads();

    f2_t pacc[2][4][4];                   // l1 partials [m-half][r][o-pair]
    #pragma unroll
    for (int mh = 0; mh < 2; ++mh)
        #pragma unroll
        for (int r = 0; r < 4; ++r)
            #pragma unroll
            for (int i = 0; i < 4; ++i) pacc[mh][r][i] = (f2_t){0.f, 0.f};

    const char* ap  = &Ald[lane * 16];
    const char* bpw = ftw8 + (size_t)(wave * 8) * 1024 + (size_t)lane * 16;

    // seed the depth-3 B pipeline with ng=0's chunks 0..5
    l2_t pA0 = *(const l2_t*)(bpw);
    l2_t pA1 = *(const l2_t*)(bpw + 1 * 32768);
    l2_t pB0 = *(const l2_t*)(bpw + 2 * 32768);
    l2_t pB1 = *(const l2_t*)(bpw + 3 * 32768);
    l2_t pC0 = *(const l2_t*)(bpw + 4 * 32768);
    l2_t pC1 = *(const l2_t*)(bpw + 5 * 32768);

    #pragma unroll 1
    for (int ng = 0; ng < 8; ++ng) {
        const char* bp = bpw + ng * 1024;

        f4_t acc[4][2];
        #pragma unroll
        for (int m = 0; m < 4; ++m) {
            acc[m][0] = (f4_t){0.f,0.f,0.f,0.f};
            acc[m][1] = (f4_t){0.f,0.f,0.f,0.f};
        }

        l2_t bA0 = pA0, bA1 = pA1, bB0 = pB0, bB1 = pB1, bC0 = pC0, bC1 = pC1;

        // kg 0..8: steady state, prefetch chunks 6..23 three iterations ahead
        #pragma unroll
        for (int kg = 0; kg < 9; ++kg) {
            l2_t bn0 = *(const l2_t*)(bp + (2 * kg + 6) * 32768);
            l2_t bn1 = *(const l2_t*)(bp + (2 * kg + 7) * 32768);
            KG_STEP(kg)
            bA0 = bB0; bA1 = bB1; bB0 = bC0; bB1 = bC1; bC0 = bn0; bC1 = bn1;
        }

        // hoisted epilogue operands: issued ~3 kg-iters (~300cy) before use
        const int colb = wave * 256 + ng * 32 + nl;
        float bias0 = ftb[colb];
        float bias1 = ftb[colb + 16];
        f2_t lo2[2][4], hi2[2][4];
        {
            const f2_t* q0  = (const f2_t*)(l1wT + (size_t)colb * 8);
            const f2_t* q0h = (const f2_t*)(l1wT + (size_t)(colb + 1024) * 8);
            const f2_t* q1  = (const f2_t*)(l1wT + (size_t)(colb + 16) * 8);
            const f2_t* q1h = (const f2_t*)(l1wT + (size_t)(colb + 1040) * 8);
            #pragma unroll
            for (int i = 0; i < 4; ++i) {
                lo2[0][i] = q0[i];  hi2[0][i] = q0h[i];
                lo2[1][i] = q1[i];  hi2[1][i] = q1h[i];
            }
        }

        // kg 9..11: drain the pipeline (no more B loads this ng)
        #pragma unroll
        for (int kg = 9; kg < 12; ++kg) {
            KG_STEP(kg)
            bA0 = bB0; bA1 = bB1; bB0 = bC0; bB1 = bC1;
        }

        // cross-ng software pipeline: issue next ng's seed loads now so the
        // epilogue VALU below hides their L2 latency
        if (ng < 7) {
            const char* bpn = bpw + (ng + 1) * 1024;
            pA0 = *(const l2_t*)(bpn);
            pA1 = *(const l2_t*)(bpn + 1 * 32768);
            pB0 = *(const l2_t*)(bpn + 2 * 32768);
            pB1 = *(const l2_t*)(bpn + 3 * 32768);
            pC0 = *(const l2_t*)(bpn + 4 * 32768);
            pC1 = *(const l2_t*)(bpn + 5 * 32768);
        }

        // epilogue: blend + clip + l1 partial dot over this ng's 32 columns
        #pragma unroll
        for (int nb = 0; nb < 2; ++nb) {
            float bias = nb ? bias1 : bias0;
            #pragma unroll
            for (int r = 0; r < 4; ++r) {
                float w0 = fmaf(acc[0][nb][r], INV_SCALE, bias);
                float w1 = fmaf(acc[1][nb][r], INV_SCALE, bias);
                float b0 = fmaf(acc[2][nb][r], INV_SCALE, bias);
                float b1 = fmaf(acc[3][nb][r], INV_SCALE, bias);
                float d0 = w0 - b0, d1 = w1 - b1;
                float f0 = clip01(fmaf( s_lo[r], d0, b0));   // stm*w + (1-stm)*b
                float g0 = clip01(fmaf(-s_lo[r], d0, w0));   // stm*b + (1-stm)*w
                float f1 = clip01(fmaf( s_hi[r], d1, b1));
                float g1 = clip01(fmaf(-s_hi[r], d1, w1));
                #pragma unroll
                for (int i = 0; i < 4; ++i) {
                    pacc[0][r][i] += f0 * lo2[nb][i] + g0 * hi2[nb][i];
                    pacc[1][r][i] += f1 * lo2[nb][i] + g1 * hi2[nb][i];
                }
            }
        }
    }

    // reduce partials across the 16 column-lanes
    #pragma unroll
    for (int m = 1; m < 16; m <<= 1)
        #pragma unroll
        for (int mh = 0; mh < 2; ++mh)
            #pragma unroll
            for (int r = 0; r < 4; ++r)
                #pragma unroll
                for (int i = 0; i < 4; ++i) {
                    pacc[mh][r][i].x += __shfl_xor(pacc[mh][r][i].x, m);
                    pacc[mh][r][i].y += __shfl_xor(pacc[mh][r][i].y, m);
                }

    if (nl == 0) {
        #pragma unroll
        for (int mh = 0; mh < 2; ++mh)
            #pragma unroll
            for (int r = 0; r < 4; ++r)
                #pragma unroll
                for (int i = 0; i < 4; ++i) {
                    l1part[wave][mh * 16 + q * 4 + r][2*i]   = pacc[mh][r][i].x;
                    l1part[wave][mh * 16 + q * 4 + r][2*i+1] = pacc[mh][r][i].y;
                }
    }
    __syncthreads();

    // tail MLP: l1 bias+clip -> l2 -> l3 -> sigmoid
    if (t < 32) {
        float v[8];
        #pragma unroll
        for (int o = 0; o < 8; ++o)
            v[o] = clip01(l1part[0][t][o] + l1part[1][t][o] +
                          l1part[2][t][o] + l1part[3][t][o] + l1b[o]);
        float raw = l3b[0];
        #pragma unroll
        for (int u = 0; u < 32; ++u) {
            float h = l2b[u];
            #pragma unroll
            for (int o = 0; o < 8; ++o) h = fmaf(v[o], l2w[u * 8 + o], h);
            h = clip01(h);
            raw = fmaf(h, l3w[u], raw);
        }
        out[s0 + t]           = 1.0f / (1.0f + expf(-raw));
        out[B_TOTAL + s0 + t] = raw;
    }
}

extern "C" void kernel_launch(void* const* d_in, const int* in_sizes, int n_in,
                              void* d_out, int out_size, void* d_ws, size_t ws_size,
                              hipStream_t stream)
{
    (void)in_sizes; (void)n_in; (void)out_size; (void)ws_size;
    const float* wf  = (const float*)d_in[0];
    const float* bf  = (const float*)d_in[1];
    const float* stm = (const float*)d_in[2];
    const float* ftw = (const float*)d_in[3];
    const float* ftb = (const float*)d_in[4];
    const float* l1w = (const float*)d_in[5];
    const float* l1b = (const float*)d_in[6];
    const float* l2w = (const float*)d_in[7];
    const float* l2b = (const float*)d_in[8];
    const float* l3w = (const float*)d_in[9];
    const float* l3b = (const float*)d_in[10];
    char*  ws8  = (char*)d_ws;                      // 768 KB packed fp8 ft_w
    float* l1wT = (float*)(ws8 + L1WT_OFF);         // 64 KB transposed l1w

    hipLaunchKernelGGL(pack_ftw_kernel, dim3(192), dim3(256), 0, stream, ftw, ws8);
    hipLaunchKernelGGL(pack_l1w_kernel, dim3(64), dim3(256), 0, stream, l1w, l1wT);
    hipLaunchKernelGGL(nnue_fused_kernel, dim3(2048), dim3(256), 0, stream,
                       wf, bf, stm, ws8, ftb, l1wT, l1b, l2w, l2b, l3w, l3b,
                       (float*)d_out);
}

// Round 2
// 923.751 us; speedup vs baseline: 1.1068x; 1.1068x over previous
//
#include <hip/hip_runtime.h>
#include <cmath>

typedef float f4_t __attribute__((ext_vector_type(4)));
typedef float f2_t __attribute__((ext_vector_type(2)));
typedef long  l2_t __attribute__((ext_vector_type(2)));

#define B_TOTAL   65536
#define FTW_SCALE 1024.0f
#define INV_SCALE (1.0f/1024.0f)
#define L1WT_OFF  (768 * 1024)

__device__ __forceinline__ int pk8(float a, float b, float c, float d) {
    int v = __builtin_amdgcn_cvt_pk_fp8_f32(a, b, 0, false);
    return  __builtin_amdgcn_cvt_pk_fp8_f32(c, d, v, true);
}
__device__ __forceinline__ float clip01(float x) { return fminf(fmaxf(x, 0.f), 1.f); }

// ---------------------------------------------------------------------------
// Pack ft_w [1024][768] fp32 -> fp8(e4m3, x1024) in frag-pair order:
//   ws[(kk*32 + ncp)*1024 + lane*16]  holds cols ncp*32+[0,32) for k-chunk kk
//   bytes 0-7 = cols +[0,16) frag, bytes 8-15 = cols +[16,32) frag.
// ---------------------------------------------------------------------------
__global__ void pack_ftw_kernel(const float* __restrict__ ftw, char* __restrict__ ws)
{
    int t    = blockIdx.x * 256 + threadIdx.x;   // 0..49151
    int lane = t & 63;
    int ncp  = (t >> 6) & 31;
    int kk   = t >> 11;                          // 0..23
    int nl = lane & 15, q = (lane >> 4) & 3;
    int k0 = kk * 32 + q * 8;
    const float* p0 = ftw + (size_t)(ncp * 32 + nl) * 768 + k0;
    const float* p1 = p0 + 16 * 768;
    float4 x0 = *(const float4*)p0;
    float4 x1 = *(const float4*)(p0 + 4);
    float4 y0 = *(const float4*)p1;
    float4 y1 = *(const float4*)(p1 + 4);
    int4 o;
    o.x = pk8(x0.x*FTW_SCALE, x0.y*FTW_SCALE, x0.z*FTW_SCALE, x0.w*FTW_SCALE);
    o.y = pk8(x1.x*FTW_SCALE, x1.y*FTW_SCALE, x1.z*FTW_SCALE, x1.w*FTW_SCALE);
    o.z = pk8(y0.x*FTW_SCALE, y0.y*FTW_SCALE, y0.z*FTW_SCALE, y0.w*FTW_SCALE);
    o.w = pk8(y1.x*FTW_SCALE, y1.y*FTW_SCALE, y1.z*FTW_SCALE, y1.w*FTW_SCALE);
    *(int4*)(ws + (size_t)t * 16) = o;
}

// ---------------------------------------------------------------------------
// Transpose l1_w [8][2048] -> l1wT [2048][8]: one column's 8 output-weights
// become contiguous (vector-loadable) instead of 16 stride-8KB scalars.
// ---------------------------------------------------------------------------
__global__ void pack_l1w_kernel(const float* __restrict__ l1w, float* __restrict__ l1wT)
{
    int t = blockIdx.x * 256 + threadIdx.x;   // 0..16383
    int c = t >> 3, o = t & 7;
    l1wT[t] = l1w[o * 2048 + c];
}

// one half-kg worth of MFMAs: 4 m-tiles x 2 n-frags against one B reg pair
#define HALF_STEP(AW, AB, BV)                                                                  \
    acc[0][0] = __builtin_amdgcn_mfma_f32_16x16x32_fp8_fp8((AW).x, (BV).x, acc[0][0], 0,0,0);  \
    acc[1][0] = __builtin_amdgcn_mfma_f32_16x16x32_fp8_fp8((AW).y, (BV).x, acc[1][0], 0,0,0);  \
    acc[2][0] = __builtin_amdgcn_mfma_f32_16x16x32_fp8_fp8((AB).x, (BV).x, acc[2][0], 0,0,0);  \
    acc[3][0] = __builtin_amdgcn_mfma_f32_16x16x32_fp8_fp8((AB).y, (BV).x, acc[3][0], 0,0,0);  \
    acc[0][1] = __builtin_amdgcn_mfma_f32_16x16x32_fp8_fp8((AW).x, (BV).y, acc[0][1], 0,0,0);  \
    acc[1][1] = __builtin_amdgcn_mfma_f32_16x16x32_fp8_fp8((AW).y, (BV).y, acc[1][1], 0,0,0);  \
    acc[2][1] = __builtin_amdgcn_mfma_f32_16x16x32_fp8_fp8((AB).x, (BV).y, acc[2][1], 0,0,0);  \
    acc[3][1] = __builtin_amdgcn_mfma_f32_16x16x32_fp8_fp8((AB).y, (BV).y, acc[3][1], 0,0,0);

// ---------------------------------------------------------------------------
// Fused kernel. 1 block = 32 samples; A (w+b, fp8) in LDS fragment order.
// Round 2: register-disciplined latency hiding.
//   - rolling 4-reg B pipeline (bc/bm), prefetch distance 2 kg (~200cy >= L2)
//   - prefetch WRAPS into next ng's chunks 0-3 at kg=10/11, so the rolling
//     regs carry next ng's seed across the epilogue (zero extra registers)
//   - initial seed issued before staging (arrives under the staging barrier)
//   - l1wT vectorized epilogue loads, point-of-use, named scalars only
//   - s_setprio(1) around the MFMA section (independent waves, no barriers)
// ---------------------------------------------------------------------------
__global__ __launch_bounds__(256, 3) void nnue_fused_kernel(
    const float* __restrict__ wf,  const float* __restrict__ bfeat,
    const float* __restrict__ stm, const char*  __restrict__ ftw8,
    const float* __restrict__ ftb, const float* __restrict__ l1wT,
    const float* __restrict__ l1b, const float* __restrict__ l2w,
    const float* __restrict__ l2b, const float* __restrict__ l3w,
    const float* __restrict__ l3b, float* __restrict__ out)
{
    __shared__ char  Ald[24 * 2048];      // 48 KB: [(kk*2+p)*1024 + lane*16]
    __shared__ float l1part[4][32][8];    // 4 KB

    const int t    = threadIdx.x;
    const int lane = t & 63;
    const int wave = t >> 6;
    const int nl   = lane & 15;
    const int q    = (lane >> 4) & 3;
    const int s0   = blockIdx.x * 32;

    const char* bpw = ftw8 + (size_t)(wave * 8) * 1024 + (size_t)lane * 16;

    // seed the rolling B pipeline with ng=0 chunks 0..3 -- these loads hide
    // under the whole staging phase + barrier below.
    l2_t bc0 = *(const l2_t*)(bpw);
    l2_t bc1 = *(const l2_t*)(bpw + 1 * 32768);
    l2_t bm0 = *(const l2_t*)(bpw + 2 * 32768);
    l2_t bm1 = *(const l2_t*)(bpw + 3 * 32768);

    // ---- stage A: fp32 -> fp8 directly into fragment-pair layout ----
    {
        const int kpar = t >> 7;
        const int tt   = t & 127;
        const int p    = tt >> 6;         // 0 = white, 1 = black
        const int sl   = tt & 63;
        const int snl  = sl & 15, sq = (sl >> 4) & 3;
        const float* base = p ? bfeat : wf;
        const float* r0 = base + (size_t)(s0 + snl) * 768;
        const float* r1 = r0 + 16 * 768;
        char* dst = &Ald[p * 1024 + sl * 16];
        #pragma unroll 4
        for (int pass = 0; pass < 12; ++pass) {
            int kk = pass * 2 + kpar;
            int k0 = kk * 32 + sq * 8;
            float4 x0 = *(const float4*)(r0 + k0);
            float4 x1 = *(const float4*)(r0 + k0 + 4);
            float4 y0 = *(const float4*)(r1 + k0);
            float4 y1 = *(const float4*)(r1 + k0 + 4);
            int4 o;
            o.x = pk8(x0.x, x0.y, x0.z, x0.w);   // rows 0-15
            o.y = pk8(x1.x, x1.y, x1.z, x1.w);
            o.z = pk8(y0.x, y0.y, y0.z, y0.w);   // rows 16-31
            o.w = pk8(y1.x, y1.y, y1.z, y1.w);
            *(int4*)(dst + kk * 2048) = o;
        }
    }

    float s_lo[4], s_hi[4];
    #pragma unroll
    for (int r = 0; r < 4; ++r) {
        s_lo[r] = stm[s0 + q * 4 + r];
        s_hi[r] = stm[s0 + 16 + q * 4 + r];
    }

    __syncthreads();

    f2_t pacc[2][4][4];                   // l1 partials [m-half][r][o-pair]
    #pragma unroll
    for (int mh = 0; mh < 2; ++mh)
        #pragma unroll
        for (int r = 0; r < 4; ++r)
            #pragma unroll
            for (int i = 0; i < 4; ++i) pacc[mh][r][i] = (f2_t){0.f, 0.f};

    const char* ap = &Ald[lane * 16];

    #pragma unroll 1
    for (int ng = 0; ng < 8; ++ng) {
        const char* bp  = bpw + ng * 1024;
        // next-ng base for the wrapping prefetch (ng=7 harmlessly reloads self)
        const char* bpn = bp + (ng < 7 ? 1024 : 0);

        f4_t acc[4][2];
        #pragma unroll
        for (int m = 0; m < 4; ++m) {
            acc[m][0] = (f4_t){0.f,0.f,0.f,0.f};
            acc[m][1] = (f4_t){0.f,0.f,0.f,0.f};
        }

        __builtin_amdgcn_s_setprio(1);
        #pragma unroll
        for (int kg = 0; kg < 12; ++kg) {
            // prefetch chunks 2kg+4, 2kg+5 (distance 2 kg ~ 200cy); at
            // kg=10/11 this wraps into the NEXT ng's chunks 0..3, carrying
            // the seed across the epilogue in the same rolling registers.
            const int p0 = 2 * kg + 4;
            const int p1 = 2 * kg + 5;
            l2_t bn0, bn1;
            if (p0 < 24) {
                bn0 = *(const l2_t*)(bp + p0 * 32768);
                bn1 = *(const l2_t*)(bp + p1 * 32768);
            } else {
                bn0 = *(const l2_t*)(bpn + (p0 - 24) * 32768);
                bn1 = *(const l2_t*)(bpn + (p1 - 24) * 32768);
            }

            l2_t aw  = *(const l2_t*)(ap + (2 * kg) * 2048);
            l2_t ab  = *(const l2_t*)(ap + (2 * kg) * 2048 + 1024);
            HALF_STEP(aw, ab, bc0)
            l2_t aw2 = *(const l2_t*)(ap + (2 * kg + 1) * 2048);
            l2_t ab2 = *(const l2_t*)(ap + (2 * kg + 1) * 2048 + 1024);
            HALF_STEP(aw2, ab2, bc1)

            bc0 = bm0; bc1 = bm1; bm0 = bn0; bm1 = bn1;
        }
        __builtin_amdgcn_s_setprio(0);

        // epilogue: blend + clip + l1 partial dot over this ng's 32 columns.
        // All loads vectorized via l1wT, point-of-use, named scalars only.
        #pragma unroll
        for (int nb = 0; nb < 2; ++nb) {
            const int col = wave * 256 + ng * 32 + nb * 16 + nl;
            float bias = ftb[col];
            const float* wl = l1wT + (size_t)col * 8;
            f2_t L0 = *(const f2_t*)(wl);
            f2_t L1 = *(const f2_t*)(wl + 2);
            f2_t L2 = *(const f2_t*)(wl + 4);
            f2_t L3 = *(const f2_t*)(wl + 6);
            f2_t H0 = *(const f2_t*)(wl + 8192);      // col+1024
            f2_t H1 = *(const f2_t*)(wl + 8192 + 2);
            f2_t H2 = *(const f2_t*)(wl + 8192 + 4);
            f2_t H3 = *(const f2_t*)(wl + 8192 + 6);
            #pragma unroll
            for (int r = 0; r < 4; ++r) {
                float w0 = fmaf(acc[0][nb][r], INV_SCALE, bias);
                float w1 = fmaf(acc[1][nb][r], INV_SCALE, bias);
                float b0 = fmaf(acc[2][nb][r], INV_SCALE, bias);
                float b1 = fmaf(acc[3][nb][r], INV_SCALE, bias);
                float d0 = w0 - b0, d1 = w1 - b1;
                float f0 = clip01(fmaf( s_lo[r], d0, b0));   // stm*w + (1-stm)*b
                float g0 = clip01(fmaf(-s_lo[r], d0, w0));   // stm*b + (1-stm)*w
                float f1 = clip01(fmaf( s_hi[r], d1, b1));
                float g1 = clip01(fmaf(-s_hi[r], d1, w1));
                pacc[0][r][0] += f0 * L0 + g0 * H0;
                pacc[0][r][1] += f0 * L1 + g0 * H1;
                pacc[0][r][2] += f0 * L2 + g0 * H2;
                pacc[0][r][3] += f0 * L3 + g0 * H3;
                pacc[1][r][0] += f1 * L0 + g1 * H0;
                pacc[1][r][1] += f1 * L1 + g1 * H1;
                pacc[1][r][2] += f1 * L2 + g1 * H2;
                pacc[1][r][3] += f1 * L3 + g1 * H3;
            }
        }
    }

    // reduce partials across the 16 column-lanes
    #pragma unroll
    for (int m = 1; m < 16; m <<= 1)
        #pragma unroll
        for (int mh = 0; mh < 2; ++mh)
            #pragma unroll
            for (int r = 0; r < 4; ++r)
                #pragma unroll
                for (int i = 0; i < 4; ++i) {
                    pacc[mh][r][i].x += __shfl_xor(pacc[mh][r][i].x, m);
                    pacc[mh][r][i].y += __shfl_xor(pacc[mh][r][i].y, m);
                }

    if (nl == 0) {
        #pragma unroll
        for (int mh = 0; mh < 2; ++mh)
            #pragma unroll
            for (int r = 0; r < 4; ++r)
                #pragma unroll
                for (int i = 0; i < 4; ++i) {
                    l1part[wave][mh * 16 + q * 4 + r][2*i]   = pacc[mh][r][i].x;
                    l1part[wave][mh * 16 + q * 4 + r][2*i+1] = pacc[mh][r][i].y;
                }
    }
    __syncthreads();

    // tail MLP: l1 bias+clip -> l2 -> l3 -> sigmoid
    if (t < 32) {
        float v[8];
        #pragma unroll
        for (int o = 0; o < 8; ++o)
            v[o] = clip01(l1part[0][t][o] + l1part[1][t][o] +
                          l1part[2][t][o] + l1part[3][t][o] + l1b[o]);
        float raw = l3b[0];
        #pragma unroll
        for (int u = 0; u < 32; ++u) {
            float h = l2b[u];
            #pragma unroll
            for (int o = 0; o < 8; ++o) h = fmaf(v[o], l2w[u * 8 + o], h);
            h = clip01(h);
            raw = fmaf(h, l3w[u], raw);
        }
        out[s0 + t]           = 1.0f / (1.0f + expf(-raw));
        out[B_TOTAL + s0 + t] = raw;
    }
}

extern "C" void kernel_launch(void* const* d_in, const int* in_sizes, int n_in,
                              void* d_out, int out_size, void* d_ws, size_t ws_size,
                              hipStream_t stream)
{
    (void)in_sizes; (void)n_in; (void)out_size; (void)ws_size;
    const float* wf  = (const float*)d_in[0];
    const float* bf  = (const float*)d_in[1];
    const float* stm = (const float*)d_in[2];
    const float* ftw = (const float*)d_in[3];
    const float* ftb = (const float*)d_in[4];
    const float* l1w = (const float*)d_in[5];
    const float* l1b = (const float*)d_in[6];
    const float* l2w = (const float*)d_in[7];
    const float* l2b = (const float*)d_in[8];
    const float* l3w = (const float*)d_in[9];
    const float* l3b = (const float*)d_in[10];
    char*  ws8  = (char*)d_ws;                      // 768 KB packed fp8 ft_w
    float* l1wT = (float*)(ws8 + L1WT_OFF);         // 64 KB transposed l1w

    hipLaunchKernelGGL(pack_ftw_kernel, dim3(192), dim3(256), 0, stream, ftw, ws8);
    hipLaunchKernelGGL(pack_l1w_kernel, dim3(64), dim3(256), 0, stream, l1w, l1wT);
    hipLaunchKernelGGL(nnue_fused_kernel, dim3(2048), dim3(256), 0, stream,
                       wf, bf, stm, ws8, ftb, l1wT, l1b, l2w, l2b, l3w, l3b,
                       (float*)d_out);
}

// Round 3
// 861.751 us; speedup vs baseline: 1.1864x; 1.0719x over previous
//
#include <hip/hip_runtime.h>
#include <cmath>

typedef float f4_t __attribute__((ext_vector_type(4)));
typedef float f2_t __attribute__((ext_vector_type(2)));
typedef long  l2_t __attribute__((ext_vector_type(2)));

#define B_TOTAL   65536
#define FTW_SCALE 1024.0f
#define INV_SCALE (1.0f/1024.0f)
#define L1WT_OFF  (768 * 1024)

__device__ __forceinline__ int pk8(float a, float b, float c, float d) {
    int v = __builtin_amdgcn_cvt_pk_fp8_f32(a, b, 0, false);
    return  __builtin_amdgcn_cvt_pk_fp8_f32(c, d, v, true);
}
__device__ __forceinline__ float clip01(float x) { return fminf(fmaxf(x, 0.f), 1.f); }

// ---------------------------------------------------------------------------
// Pack ft_w [1024][768] fp32 -> fp8(e4m3, x1024) in frag-pair order:
//   ws[(kk*32 + ncp)*1024 + lane*16]  holds cols ncp*32+[0,32) for k-chunk kk
//   bytes 0-7 = cols +[0,16) frag, bytes 8-15 = cols +[16,32) frag.
// ---------------------------------------------------------------------------
__global__ void pack_ftw_kernel(const float* __restrict__ ftw, char* __restrict__ ws)
{
    int t    = blockIdx.x * 256 + threadIdx.x;   // 0..49151
    int lane = t & 63;
    int ncp  = (t >> 6) & 31;
    int kk   = t >> 11;                          // 0..23
    int nl = lane & 15, q = (lane >> 4) & 3;
    int k0 = kk * 32 + q * 8;
    const float* p0 = ftw + (size_t)(ncp * 32 + nl) * 768 + k0;
    const float* p1 = p0 + 16 * 768;
    float4 x0 = *(const float4*)p0;
    float4 x1 = *(const float4*)(p0 + 4);
    float4 y0 = *(const float4*)p1;
    float4 y1 = *(const float4*)(p1 + 4);
    int4 o;
    o.x = pk8(x0.x*FTW_SCALE, x0.y*FTW_SCALE, x0.z*FTW_SCALE, x0.w*FTW_SCALE);
    o.y = pk8(x1.x*FTW_SCALE, x1.y*FTW_SCALE, x1.z*FTW_SCALE, x1.w*FTW_SCALE);
    o.z = pk8(y0.x*FTW_SCALE, y0.y*FTW_SCALE, y0.z*FTW_SCALE, y0.w*FTW_SCALE);
    o.w = pk8(y1.x*FTW_SCALE, y1.y*FTW_SCALE, y1.z*FTW_SCALE, y1.w*FTW_SCALE);
    *(int4*)(ws + (size_t)t * 16) = o;
}

// ---------------------------------------------------------------------------
// Transpose l1_w [8][2048] -> l1wT [2048][8]: one column's 8 output-weights
// become contiguous (vector-loadable) instead of 16 stride-8KB scalars.
// ---------------------------------------------------------------------------
__global__ void pack_l1w_kernel(const float* __restrict__ l1w, float* __restrict__ l1wT)
{
    int t = blockIdx.x * 256 + threadIdx.x;   // 0..16383
    int c = t >> 3, o = t & 7;
    l1wT[t] = l1w[o * 2048 + c];
}

// one half-kg worth of MFMAs: 4 m-tiles x 2 n-frags against one B reg pair
#define HALF_STEP(AW, AB, BV)                                                                  \
    acc[0][0] = __builtin_amdgcn_mfma_f32_16x16x32_fp8_fp8((AW).x, (BV).x, acc[0][0], 0,0,0);  \
    acc[1][0] = __builtin_amdgcn_mfma_f32_16x16x32_fp8_fp8((AW).y, (BV).x, acc[1][0], 0,0,0);  \
    acc[2][0] = __builtin_amdgcn_mfma_f32_16x16x32_fp8_fp8((AB).x, (BV).x, acc[2][0], 0,0,0);  \
    acc[3][0] = __builtin_amdgcn_mfma_f32_16x16x32_fp8_fp8((AB).y, (BV).x, acc[3][0], 0,0,0);  \
    acc[0][1] = __builtin_amdgcn_mfma_f32_16x16x32_fp8_fp8((AW).x, (BV).y, acc[0][1], 0,0,0);  \
    acc[1][1] = __builtin_amdgcn_mfma_f32_16x16x32_fp8_fp8((AW).y, (BV).y, acc[1][1], 0,0,0);  \
    acc[2][1] = __builtin_amdgcn_mfma_f32_16x16x32_fp8_fp8((AB).x, (BV).y, acc[2][1], 0,0,0);  \
    acc[3][1] = __builtin_amdgcn_mfma_f32_16x16x32_fp8_fp8((AB).y, (BV).y, acc[3][1], 0,0,0);

// ---------------------------------------------------------------------------
// Fused kernel. 1 block = 32 samples; A (w+b, fp8) in LDS fragment order.
// Round 3:
//   - amdgpu_waves_per_eu(3,3): occupancy is LDS-bound at 3 blocks/CU =
//     3 waves/EU; stop the backend targeting the 6-wave (84-VGPR) tier and
//     spilling loop state to scratch (R1/R2 regression: WRITE_SIZE 360-480MB).
//   - depth-2 rolling B prefetch (issue-to-use ~200cy >= L2 hit latency),
//     reseeded per ng so nothing lives across the epilogue.
//   - l1wT vectorized epilogue loads, point-of-use, named scalars only.
//   - s_setprio(1) around the MFMA loop (waves are barrier-free there).
// ---------------------------------------------------------------------------
__global__ __launch_bounds__(256)
__attribute__((amdgpu_waves_per_eu(3, 3)))
void nnue_fused_kernel(
    const float* __restrict__ wf,  const float* __restrict__ bfeat,
    const float* __restrict__ stm, const char*  __restrict__ ftw8,
    const float* __restrict__ ftb, const float* __restrict__ l1wT,
    const float* __restrict__ l1b, const float* __restrict__ l2w,
    const float* __restrict__ l2b, const float* __restrict__ l3w,
    const float* __restrict__ l3b, float* __restrict__ out)
{
    __shared__ char  Ald[24 * 2048];      // 48 KB: [(kk*2+p)*1024 + lane*16]
    __shared__ float l1part[4][32][8];    // 4 KB

    const int t    = threadIdx.x;
    const int lane = t & 63;
    const int wave = t >> 6;
    const int nl   = lane & 15;
    const int q    = (lane >> 4) & 3;
    const int s0   = blockIdx.x * 32;

    // ---- stage A: fp32 -> fp8 directly into fragment-pair layout ----
    {
        const int kpar = t >> 7;
        const int tt   = t & 127;
        const int p    = tt >> 6;         // 0 = white, 1 = black
        const int sl   = tt & 63;
        const int snl  = sl & 15, sq = (sl >> 4) & 3;
        const float* base = p ? bfeat : wf;
        const float* r0 = base + (size_t)(s0 + snl) * 768;
        const float* r1 = r0 + 16 * 768;
        char* dst = &Ald[p * 1024 + sl * 16];
        #pragma unroll 4
        for (int pass = 0; pass < 12; ++pass) {
            int kk = pass * 2 + kpar;
            int k0 = kk * 32 + sq * 8;
            float4 x0 = *(const float4*)(r0 + k0);
            float4 x1 = *(const float4*)(r0 + k0 + 4);
            float4 y0 = *(const float4*)(r1 + k0);
            float4 y1 = *(const float4*)(r1 + k0 + 4);
            int4 o;
            o.x = pk8(x0.x, x0.y, x0.z, x0.w);   // rows 0-15
            o.y = pk8(x1.x, x1.y, x1.z, x1.w);
            o.z = pk8(y0.x, y0.y, y0.z, y0.w);   // rows 16-31
            o.w = pk8(y1.x, y1.y, y1.z, y1.w);
            *(int4*)(dst + kk * 2048) = o;
        }
    }

    float s_lo[4], s_hi[4];
    #pragma unroll
    for (int r = 0; r < 4; ++r) {
        s_lo[r] = stm[s0 + q * 4 + r];
        s_hi[r] = stm[s0 + 16 + q * 4 + r];
    }

    __syncthreads();

    f2_t pacc[2][4][4];                   // l1 partials [m-half][r][o-pair]
    #pragma unroll
    for (int mh = 0; mh < 2; ++mh)
        #pragma unroll
        for (int r = 0; r < 4; ++r)
            #pragma unroll
            for (int i = 0; i < 4; ++i) pacc[mh][r][i] = (f2_t){0.f, 0.f};

    const char* ap  = &Ald[lane * 16];
    const char* bpw = ftw8 + (size_t)(wave * 8) * 1024 + (size_t)lane * 16;

    #pragma unroll 1
    for (int ng = 0; ng < 8; ++ng) {
        const char* bp = bpw + ng * 1024;

        // reseed the rolling depth-2 pipeline (chunks 0..3); nothing from the
        // pipeline is live across the epilogue below.
        l2_t bc0 = *(const l2_t*)(bp);
        l2_t bc1 = *(const l2_t*)(bp + 1 * 32768);
        l2_t bm0 = *(const l2_t*)(bp + 2 * 32768);
        l2_t bm1 = *(const l2_t*)(bp + 3 * 32768);

        f4_t acc[4][2];
        #pragma unroll
        for (int m = 0; m < 4; ++m) {
            acc[m][0] = (f4_t){0.f,0.f,0.f,0.f};
            acc[m][1] = (f4_t){0.f,0.f,0.f,0.f};
        }

        __builtin_amdgcn_s_setprio(1);
        #pragma unroll
        for (int kg = 0; kg < 12; ++kg) {
            // prefetch chunks 2kg+4, 2kg+5 (distance 2 kg ~ 200cy >= L2 hit)
            l2_t bn0, bn1;
            if (kg < 10) {
                bn0 = *(const l2_t*)(bp + (2 * kg + 4) * 32768);
                bn1 = *(const l2_t*)(bp + (2 * kg + 5) * 32768);
            }

            l2_t aw  = *(const l2_t*)(ap + (2 * kg) * 2048);
            l2_t ab  = *(const l2_t*)(ap + (2 * kg) * 2048 + 1024);
            HALF_STEP(aw, ab, bc0)
            l2_t aw2 = *(const l2_t*)(ap + (2 * kg + 1) * 2048);
            l2_t ab2 = *(const l2_t*)(ap + (2 * kg + 1) * 2048 + 1024);
            HALF_STEP(aw2, ab2, bc1)

            bc0 = bm0; bc1 = bm1;
            if (kg < 10) { bm0 = bn0; bm1 = bn1; }
        }
        __builtin_amdgcn_s_setprio(0);

        // epilogue: blend + clip + l1 partial dot over this ng's 32 columns.
        // All loads vectorized via l1wT, point-of-use, named scalars only.
        #pragma unroll
        for (int nb = 0; nb < 2; ++nb) {
            const int col = wave * 256 + ng * 32 + nb * 16 + nl;
            float bias = ftb[col];
            const float* wl = l1wT + (size_t)col * 8;
            f2_t L0 = *(const f2_t*)(wl);
            f2_t L1 = *(const f2_t*)(wl + 2);
            f2_t L2 = *(const f2_t*)(wl + 4);
            f2_t L3 = *(const f2_t*)(wl + 6);
            f2_t H0 = *(const f2_t*)(wl + 8192);      // col+1024
            f2_t H1 = *(const f2_t*)(wl + 8192 + 2);
            f2_t H2 = *(const f2_t*)(wl + 8192 + 4);
            f2_t H3 = *(const f2_t*)(wl + 8192 + 6);
            #pragma unroll
            for (int r = 0; r < 4; ++r) {
                float w0 = fmaf(acc[0][nb][r], INV_SCALE, bias);
                float w1 = fmaf(acc[1][nb][r], INV_SCALE, bias);
                float b0 = fmaf(acc[2][nb][r], INV_SCALE, bias);
                float b1 = fmaf(acc[3][nb][r], INV_SCALE, bias);
                float d0 = w0 - b0, d1 = w1 - b1;
                float f0 = clip01(fmaf( s_lo[r], d0, b0));   // stm*w + (1-stm)*b
                float g0 = clip01(fmaf(-s_lo[r], d0, w0));   // stm*b + (1-stm)*w
                float f1 = clip01(fmaf( s_hi[r], d1, b1));
                float g1 = clip01(fmaf(-s_hi[r], d1, w1));
                pacc[0][r][0] += f0 * L0 + g0 * H0;
                pacc[0][r][1] += f0 * L1 + g0 * H1;
                pacc[0][r][2] += f0 * L2 + g0 * H2;
                pacc[0][r][3] += f0 * L3 + g0 * H3;
                pacc[1][r][0] += f1 * L0 + g1 * H0;
                pacc[1][r][1] += f1 * L1 + g1 * H1;
                pacc[1][r][2] += f1 * L2 + g1 * H2;
                pacc[1][r][3] += f1 * L3 + g1 * H3;
            }
        }
    }

    // reduce partials across the 16 column-lanes
    #pragma unroll
    for (int m = 1; m < 16; m <<= 1)
        #pragma unroll
        for (int mh = 0; mh < 2; ++mh)
            #pragma unroll
            for (int r = 0; r < 4; ++r)
                #pragma unroll
                for (int i = 0; i < 4; ++i) {
                    pacc[mh][r][i].x += __shfl_xor(pacc[mh][r][i].x, m);
                    pacc[mh][r][i].y += __shfl_xor(pacc[mh][r][i].y, m);
                }

    if (nl == 0) {
        #pragma unroll
        for (int mh = 0; mh < 2; ++mh)
            #pragma unroll
            for (int r = 0; r < 4; ++r)
                #pragma unroll
                for (int i = 0; i < 4; ++i) {
                    l1part[wave][mh * 16 + q * 4 + r][2*i]   = pacc[mh][r][i].x;
                    l1part[wave][mh * 16 + q * 4 + r][2*i+1] = pacc[mh][r][i].y;
                }
    }
    __syncthreads();

    // tail MLP: l1 bias+clip -> l2 -> l3 -> sigmoid
    if (t < 32) {
        float v[8];
        #pragma unroll
        for (int o = 0; o < 8; ++o)
            v[o] = clip01(l1part[0][t][o] + l1part[1][t][o] +
                          l1part[2][t][o] + l1part[3][t][o] + l1b[o]);
        float raw = l3b[0];
        #pragma unroll
        for (int u = 0; u < 32; ++u) {
            float h = l2b[u];
            #pragma unroll
            for (int o = 0; o < 8; ++o) h = fmaf(v[o], l2w[u * 8 + o], h);
            h = clip01(h);
            raw = fmaf(h, l3w[u], raw);
        }
        out[s0 + t]           = 1.0f / (1.0f + expf(-raw));
        out[B_TOTAL + s0 + t] = raw;
    }
}

extern "C" void kernel_launch(void* const* d_in, const int* in_sizes, int n_in,
                              void* d_out, int out_size, void* d_ws, size_t ws_size,
                              hipStream_t stream)
{
    (void)in_sizes; (void)n_in; (void)out_size; (void)ws_size;
    const float* wf  = (const float*)d_in[0];
    const float* bf  = (const float*)d_in[1];
    const float* stm = (const float*)d_in[2];
    const float* ftw = (const float*)d_in[3];
    const float* ftb = (const float*)d_in[4];
    const float* l1w = (const float*)d_in[5];
    const float* l1b = (const float*)d_in[6];
    const float* l2w = (const float*)d_in[7];
    const float* l2b = (const float*)d_in[8];
    const float* l3w = (const float*)d_in[9];
    const float* l3b = (const float*)d_in[10];
    char*  ws8  = (char*)d_ws;                      // 768 KB packed fp8 ft_w
    float* l1wT = (float*)(ws8 + L1WT_OFF);         // 64 KB transposed l1w

    hipLaunchKernelGGL(pack_ftw_kernel, dim3(192), dim3(256), 0, stream, ftw, ws8);
    hipLaunchKernelGGL(pack_l1w_kernel, dim3(64), dim3(256), 0, stream, l1w, l1wT);
    hipLaunchKernelGGL(nnue_fused_kernel, dim3(2048), dim3(256), 0, stream,
                       wf, bf, stm, ws8, ftb, l1wT, l1b, l2w, l2b, l3w, l3b,
                       (float*)d_out);
}